// Round 1
// baseline (191.191 us; speedup 1.0000x reference)
//
#include <hip/hip_runtime.h>

#define RES 0.1f

constexpr int B_ = 512;
constexpr int N_ = 8192;       // 2^13
constexpr int H_ = 200;
constexpr int W_ = 200;
constexpr long long TOTAL = (long long)B_ * N_;   // 4,194,304

constexpr int BLOCKS = 2048;
constexpr int TPB = 256;

__global__ __launch_bounds__(TPB) void collision_partial(
    const float* __restrict__ opState,
    const float* __restrict__ envs,
    float* __restrict__ partial)
{
    const long long stride = (long long)gridDim.x * blockDim.x;
    long long i = (long long)blockIdx.x * blockDim.x + threadIdx.x;
    float acc = 0.0f;

    for (; i < TOTAL; i += stride) {
        float2 p = ((const float2*)opState)[i];

        bool out_range = (p.x < -9.9f) | (p.x > 9.9f) |
                         (p.y < -9.9f) | (p.y > 9.9f);

        // clip(x, -9.9, 9.9) = min(max(x, -9.9), 9.9)  (matches jnp.clip)
        float px = fminf(fmaxf(p.x, -9.9f), 9.9f);
        float py = fminf(fmaxf(p.y, -9.9f), 9.9f);

        float pmx = px - 0.5f * RES;
        float pmy = py - 0.5f * RES;

        // match numpy float32: divide by 0.1f (not multiply by 10)
        int ix = (int)floorf((pmx + 10.0f) / RES);
        int iy = (int)floorf((pmy + 10.0f) / RES);

        float ipx = ((float)ix + 0.5f) * RES - 10.0f;
        float ipy = ((float)iy + 0.5f) * RES - 10.0f;

        float dx = (px - ipx) / RES;
        float dy = (py - ipy) / RES;

        int b = (int)(i >> 13);            // i / N_, N_ = 8192
        const float* m = envs + (long long)b * (H_ * W_);
        int base = ix * W_ + iy;

        // (ix,iy)&(ix,iy+1) adjacent; (ix+1,iy)&(ix+1,iy+1) adjacent
        float v00 = m[base];
        float v01 = m[base + 1];
        float v10 = m[base + W_];
        float v11 = m[base + W_ + 1];

        float vx0 = (1.0f - dx) * v00 + dx * v10;
        float vx1 = (1.0f - dx) * v01 + dx * v11;
        float v   = (1.0f - dy) * vx0 + dy * vx1;

        float dists = out_range ? -1.0f : v;
        float viod  = 10.0f * (0.3f - dists);
        float r     = viod > 0.0f ? viod : 0.0f;
        acc += r * r;
    }

    // wave-64 reduction
    #pragma unroll
    for (int off = 32; off > 0; off >>= 1)
        acc += __shfl_down(acc, off, 64);

    __shared__ float sacc[TPB / 64];
    int lane = threadIdx.x & 63;
    int wid  = threadIdx.x >> 6;
    if (lane == 0) sacc[wid] = acc;
    __syncthreads();

    if (threadIdx.x == 0) {
        float s = 0.0f;
        #pragma unroll
        for (int w = 0; w < TPB / 64; ++w) s += sacc[w];
        partial[blockIdx.x] = s;
    }
}

__global__ __launch_bounds__(256) void collision_final(
    const float* __restrict__ partial,
    float* __restrict__ out)
{
    float acc = 0.0f;
    for (int i = threadIdx.x; i < BLOCKS; i += 256)
        acc += partial[i];

    #pragma unroll
    for (int off = 32; off > 0; off >>= 1)
        acc += __shfl_down(acc, off, 64);

    __shared__ float sacc[4];
    int lane = threadIdx.x & 63;
    int wid  = threadIdx.x >> 6;
    if (lane == 0) sacc[wid] = acc;
    __syncthreads();

    if (threadIdx.x == 0) {
        float s = sacc[0] + sacc[1] + sacc[2] + sacc[3];
        out[0] = s / (float)TOTAL;
    }
}

extern "C" void kernel_launch(void* const* d_in, const int* in_sizes, int n_in,
                              void* d_out, int out_size, void* d_ws, size_t ws_size,
                              hipStream_t stream) {
    const float* opState = (const float*)d_in[0];   // (512, 8192, 2) f32
    const float* envs    = (const float*)d_in[1];   // (512, 1, 200, 200) f32
    float* out     = (float*)d_out;                 // scalar f32
    float* partial = (float*)d_ws;                  // 2048 floats of scratch

    collision_partial<<<BLOCKS, TPB, 0, stream>>>(opState, envs, partial);
    collision_final<<<1, 256, 0, stream>>>(partial, out);
}

// Round 2
// 146.126 us; speedup vs baseline: 1.3084x; 1.3084x over previous
//
#include <hip/hip_runtime.h>

#define RES 0.1f

constexpr int B_ = 512;
constexpr int N_ = 8192;        // points per batch
constexpr int H_ = 200;
constexpr int W_ = 200;
constexpr int MAP = H_ * W_;    // 40000 floats = 160,000 B LDS (gfx950 has 163,840)
constexpr long long TOTAL = (long long)B_ * N_;   // 4,194,304

constexpr int TPB = 1024;       // 16 waves

__global__ __launch_bounds__(TPB) void collision_lds(
    const float* __restrict__ opState,
    const float* __restrict__ envs,
    float* __restrict__ partial)
{
    __shared__ float smap[MAP];          // 160,000 B — fits 160 KiB gfx950 LDS
    const int b   = blockIdx.x;          // one batch per block
    const int tid = threadIdx.x;

    // ---- stage map: coalesced float4 (40000/4 = 10000 vec4) ----
    {
        const float4* m4 = (const float4*)(envs + (long long)b * MAP);
        float4* s4 = (float4*)smap;
        #pragma unroll
        for (int j = tid; j < MAP / 4; j += TPB)
            s4[j] = m4[j];
    }
    __syncthreads();

    // ---- process 8192 points of this batch: 8 per thread ----
    const float2* pts = (const float2*)opState + (long long)b * N_;
    float acc = 0.0f;

    #pragma unroll
    for (int k = 0; k < N_ / TPB; ++k) {
        const int n = tid + k * TPB;
        float2 p = pts[n];

        bool out_range = (p.x < -9.9f) | (p.x > 9.9f) |
                         (p.y < -9.9f) | (p.y > 9.9f);

        float px = fminf(fmaxf(p.x, -9.9f), 9.9f);
        float py = fminf(fmaxf(p.y, -9.9f), 9.9f);

        float pmx = px - 0.5f * RES;
        float pmy = py - 0.5f * RES;

        int ix = (int)floorf((pmx + 10.0f) * 10.0f);
        int iy = (int)floorf((pmy + 10.0f) * 10.0f);

        float ipx = ((float)ix + 0.5f) * RES - 10.0f;
        float ipy = ((float)iy + 0.5f) * RES - 10.0f;

        float dx = (px - ipx) * 10.0f;
        float dy = (py - ipy) * 10.0f;

        int base = ix * W_ + iy;
        float v00 = smap[base];
        float v01 = smap[base + 1];
        float v10 = smap[base + W_];
        float v11 = smap[base + W_ + 1];

        float vx0 = (1.0f - dx) * v00 + dx * v10;
        float vx1 = (1.0f - dx) * v01 + dx * v11;
        float v   = (1.0f - dy) * vx0 + dy * vx1;

        float dists = out_range ? -1.0f : v;
        float viod  = 10.0f * (0.3f - dists);
        float r     = viod > 0.0f ? viod : 0.0f;
        acc += r * r;
    }

    // ---- block reduction: wave64 shuffle, then cross-wave via LDS ----
    #pragma unroll
    for (int off = 32; off > 0; off >>= 1)
        acc += __shfl_down(acc, off, 64);

    __shared__ float sacc[TPB / 64];     // 16 waves
    const int lane = tid & 63;
    const int wid  = tid >> 6;
    if (lane == 0) sacc[wid] = acc;
    __syncthreads();

    if (tid == 0) {
        float s = 0.0f;
        #pragma unroll
        for (int w = 0; w < TPB / 64; ++w) s += sacc[w];
        partial[b] = s;
    }
}

__global__ __launch_bounds__(512) void collision_final(
    const float* __restrict__ partial,
    float* __restrict__ out)
{
    float acc = partial[threadIdx.x];    // exactly 512 partials

    #pragma unroll
    for (int off = 32; off > 0; off >>= 1)
        acc += __shfl_down(acc, off, 64);

    __shared__ float sacc[8];
    const int lane = threadIdx.x & 63;
    const int wid  = threadIdx.x >> 6;
    if (lane == 0) sacc[wid] = acc;
    __syncthreads();

    if (threadIdx.x == 0) {
        float s = 0.0f;
        #pragma unroll
        for (int w = 0; w < 8; ++w) s += sacc[w];
        out[0] = s / (float)TOTAL;
    }
}

extern "C" void kernel_launch(void* const* d_in, const int* in_sizes, int n_in,
                              void* d_out, int out_size, void* d_ws, size_t ws_size,
                              hipStream_t stream) {
    const float* opState = (const float*)d_in[0];   // (512, 8192, 2) f32
    const float* envs    = (const float*)d_in[1];   // (512, 1, 200, 200) f32
    float* out     = (float*)d_out;                 // scalar f32
    float* partial = (float*)d_ws;                  // 512 floats of scratch

    collision_lds<<<B_, TPB, 0, stream>>>(opState, envs, partial);
    collision_final<<<1, 512, 0, stream>>>(partial, out);
}